// Round 1
// baseline (1311.867 us; speedup 1.0000x reference)
//
#include <hip/hip_runtime.h>

// GlobalClusteringModule: greedy farthest-point (min |cosine|) selection + gather.
// B=128 batches, N=300 rows, DV=1024, DA=128, K=64 selected.
// One block per batch (1024 threads = 16 waves). All selection state in LDS.
// Dots/norms accumulated in f64 to sit as close as possible to the true values
// (np f32 reference error ~1e-6; argmin flips are the only correctness hazard).

constexpr int BB = 128;
constexpr int NN = 300;
constexpr int DV = 1024;
constexpr int DA = 128;
constexpr int KK = 64;
constexpr int THREADS = 1024;
constexpr int WAVES = 16;

__global__ __launch_bounds__(1024) void cluster_fused(
    const float* __restrict__ video,   // [B, N, DV]
    const float* __restrict__ audio,   // [B, N, DA]
    float* __restrict__ out_v,         // [B, K, DV]
    float* __restrict__ out_a)         // [B, K, DA]
{
    const int b    = blockIdx.x;
    const int tid  = threadIdx.x;
    const int lane = tid & 63;
    const int wave = tid >> 6;

    __shared__ double s_inv[NN];    // 1/(||v_r|| + EPS)
    __shared__ double s_best[NN];   // running max |cos|
    __shared__ int    s_idx[KK];
    __shared__ int    s_sorted[KK];
    __shared__ int    s_last;

    const float* vb = video + (size_t)b * NN * DV;

    // ---- 1. norms (f64 accumulate) ----
    for (int r = wave; r < NN; r += WAVES) {
        const float* row = vb + (size_t)r * DV;
        double acc = 0.0;
        #pragma unroll
        for (int j = 0; j < 16; ++j) {
            float a = row[lane + 64 * j];
            acc += (double)a * (double)a;
        }
        #pragma unroll
        for (int off = 32; off >= 1; off >>= 1)
            acc += __shfl_xor(acc, off, 64);
        if (lane == 0) s_inv[r] = 1.0 / (sqrt(acc) + 1e-5);
    }
    __syncthreads();

    // ---- step: sims vs row `last`; init or max-update best ----
    auto do_step = [&](int last, bool init) {
        const float* rl = vb + (size_t)last * DV;
        double vl[16];
        #pragma unroll
        for (int j = 0; j < 16; ++j) vl[j] = (double)rl[lane + 64 * j];
        const double invl = s_inv[last];
        for (int r = wave; r < NN; r += WAVES) {
            const float* row = vb + (size_t)r * DV;
            double acc = 0.0;
            #pragma unroll
            for (int j = 0; j < 16; ++j)
                acc += (double)row[lane + 64 * j] * vl[j];
            #pragma unroll
            for (int off = 32; off >= 1; off >>= 1)
                acc += __shfl_xor(acc, off, 64);
            if (lane == 0) {
                double sim = fabs(acc) * s_inv[r] * invl;
                s_best[r] = init ? sim : fmax(s_best[r], sim);
            }
        }
    };

    // ---- argmin over s_best (wave 0), first-index tie-break ----
    auto do_argmin = [&]() {
        if (wave == 0) {
            double v = 1e300;
            int idx = NN;
            for (int r = lane; r < NN; r += 64) {
                double bv = s_best[r];
                if (bv < v) { v = bv; idx = r; }   // increasing r keeps first min
            }
            #pragma unroll
            for (int off = 32; off >= 1; off >>= 1) {
                double ov = __shfl_xor(v, off, 64);
                int    oi = __shfl_xor(idx, off, 64);
                if (ov < v || (ov == v && oi < idx)) { v = ov; idx = oi; }
            }
            if (lane == 0) s_last = idx;
        }
    };

    // ---- 2. greedy selection ----
    do_step(0, true);
    __syncthreads();
    do_argmin();
    __syncthreads();
    if (tid == 0) { s_idx[0] = 0; s_idx[1] = s_last; }
    int last = s_last;

    for (int t = 2; t < KK; ++t) {
        do_step(last, false);
        __syncthreads();
        do_argmin();
        __syncthreads();
        last = s_last;
        if (tid == 0) s_idx[t] = last;
    }
    __syncthreads();

    // ---- 3. stable rank-sort of 64 indices (wave 0) ----
    if (wave == 0) {
        int myv = s_idx[lane];
        int rank = 0;
        for (int j = 0; j < KK; ++j) {
            int oj = s_idx[j];
            rank += (oj < myv) || (oj == myv && j < lane);
        }
        s_sorted[rank] = myv;
    }
    __syncthreads();

    // ---- 4. gather ----
    const float4* vb4 = reinterpret_cast<const float4*>(vb);
    float4* ov4 = reinterpret_cast<float4*>(out_v + (size_t)b * KK * DV);
    #pragma unroll 4
    for (int t = tid; t < KK * DV / 4; t += THREADS) {
        int k = t >> 8;          // DV/4 = 256
        int c = t & 255;
        ov4[t] = vb4[s_sorted[k] * (DV / 4) + c];
    }
    const float4* ab4 = reinterpret_cast<const float4*>(audio + (size_t)b * NN * DA);
    float4* oa4 = reinterpret_cast<float4*>(out_a + (size_t)b * KK * DA);
    for (int t = tid; t < KK * DA / 4; t += THREADS) {
        int k = t >> 5;          // DA/4 = 32
        int c = t & 31;
        oa4[t] = ab4[s_sorted[k] * (DA / 4) + c];
    }
}

extern "C" void kernel_launch(void* const* d_in, const int* in_sizes, int n_in,
                              void* d_out, int out_size, void* d_ws, size_t ws_size,
                              hipStream_t stream) {
    const float* video = (const float*)d_in[0];
    const float* audio = (const float*)d_in[1];
    float* out   = (float*)d_out;
    float* out_v = out;
    float* out_a = out + (size_t)BB * KK * DV;
    hipLaunchKernelGGL(cluster_fused, dim3(BB), dim3(THREADS), 0, stream,
                       video, audio, out_v, out_a);
}

// Round 2
// 1194.962 us; speedup vs baseline: 1.0978x; 1.0978x over previous
//
#include <hip/hip_runtime.h>
#include <math.h>

// Greedy farthest-point selection via precomputed Gram triangle.
// Pipeline (one stream, 4 kernels): norms -> Gram(|cos|, f32 stored, f64 accum)
// -> greedy selection on G -> gather.
// Scratch lives inside d_out (no ws dependence):
//   floats [0, BB*TRI)          : G triangles (23.1 MB), inside out_v region
//   floats [6,000,000, +76,800) : inv norms as f64 (B*N doubles)
//   out_a + b*KK*DA             : 64 selected indices (int bits) per batch,
//                                 written by kselect, preloaded by kgather
//                                 before it overwrites that region.

constexpr int BB = 128, NN = 300, DV = 1024, DA = 128, KK = 64;
constexpr int TRI = NN * (NN + 1) / 2;        // 45150
constexpr int ROWS_PER_GROUP = 7;             // 7 f64 rows = 57344 B LDS < 64 KB
constexpr int GROUPS = (NN + ROWS_PER_GROUP - 1) / ROWS_PER_GROUP;  // 43
constexpr int NORM_OFF = 6000000;             // float offset; > BB*TRI=5779200

__device__ __forceinline__ int tri_base(int i) { return i * NN - (i * (i - 1)) / 2; }

// ---------------- 1. inverse norms (f64) ----------------
__global__ __launch_bounds__(256) void knorm(const float* __restrict__ video,
                                             double* __restrict__ invn) {
    int b = blockIdx.x, tid = threadIdx.x, lane = tid & 63, wave = tid >> 6;
    const float* vb = video + (size_t)b * NN * DV;
    for (int r = wave; r < NN; r += 4) {
        const float* row = vb + (size_t)r * DV;
        double acc = 0.0;
        #pragma unroll
        for (int c = 0; c < 16; ++c) { float a = row[lane + 64 * c]; acc += (double)a * (double)a; }
        #pragma unroll
        for (int off = 32; off >= 1; off >>= 1) acc += __shfl_xor(acc, off, 64);
        if (lane == 0) invn[b * NN + r] = 1.0 / (sqrt(acc) + 1e-5);
    }
}

// ---------------- 2. Gram triangle ----------------
// Block = (group g, batch b), 256 threads (4 waves). i-rows [i0, i0+7) staged
// as f64 in LDS; each wave streams j-rows (j = i0+wave, +4, ...), computing 7
// dots with f64 FMA. Element ownership: lane owns pairs e = 2*lane + 128*c
// (uniform bank load on b128 LDS reads, coalesced float2 global reads).
__global__ __launch_bounds__(256) void kgram(const float* __restrict__ video,
                                             const double* __restrict__ invn,
                                             float* __restrict__ G) {
    const int g = blockIdx.x, b = blockIdx.y;
    const int i0 = g * ROWS_PER_GROUP;
    const int tid = threadIdx.x, lane = tid & 63, wave = tid >> 6;
    const int nI = min(ROWS_PER_GROUP, NN - i0);

    __shared__ double s_i[ROWS_PER_GROUP][1024];   // 57344 B
    __shared__ double s_invi[ROWS_PER_GROUP];

    const float* vb = video + (size_t)b * NN * DV;
    const double* invb = invn + b * NN;

    for (int t = tid; t < nI * 256; t += 256) {        // 256 float4 per row
        int r = t >> 8, c4 = t & 255;
        float4 v = ((const float4*)(vb + (size_t)(i0 + r) * DV))[c4];
        double2* d = (double2*)&s_i[r][c4 * 4];
        d[0] = make_double2((double)v.x, (double)v.y);
        d[1] = make_double2((double)v.z, (double)v.w);
    }
    if (tid < nI) s_invi[tid] = invb[i0 + tid];
    __syncthreads();

    float* Gb = G + (size_t)b * TRI;

    for (int j = i0 + wave; j < NN; j += 4) {
        const float2* rowj = (const float2*)(vb + (size_t)j * DV);
        double invj = invb[j];
        float2 jv[8];
        #pragma unroll
        for (int c = 0; c < 8; ++c) jv[c] = rowj[lane + 64 * c];

        double acc[8];
        #pragma unroll
        for (int r = 0; r < 8; ++r) acc[r] = 0.0;

        #pragma unroll
        for (int c = 0; c < 8; ++c) {
            double jx = (double)jv[c].x, jy = (double)jv[c].y;
            #pragma unroll
            for (int r = 0; r < ROWS_PER_GROUP; ++r) {
                double2 iv = *(const double2*)&s_i[r][2 * lane + 128 * c];
                acc[r] = fma(iv.x, jx, acc[r]);
                acc[r] = fma(iv.y, jy, acc[r]);
            }
        }

        // compacting butterfly reduce: 8 accs -> 1 per lane-octet
        double tmp[8];
        #pragma unroll
        for (int r = 0; r < 8; ++r) tmp[r] = __shfl_xor(acc[r], 32, 64);
        bool h5 = (lane & 32) != 0;
        #pragma unroll
        for (int r = 0; r < 4; ++r) acc[r] = h5 ? (acc[r + 4] + tmp[r + 4]) : (acc[r] + tmp[r]);
        #pragma unroll
        for (int r = 0; r < 4; ++r) tmp[r] = __shfl_xor(acc[r], 16, 64);
        bool h4 = (lane & 16) != 0;
        #pragma unroll
        for (int r = 0; r < 2; ++r) acc[r] = h4 ? (acc[r + 2] + tmp[r + 2]) : (acc[r] + tmp[r]);
        tmp[0] = __shfl_xor(acc[0], 8, 64);
        tmp[1] = __shfl_xor(acc[1], 8, 64);
        bool h3 = (lane & 8) != 0;
        acc[0] = h3 ? (acc[1] + tmp[1]) : (acc[0] + tmp[0]);
        acc[0] += __shfl_xor(acc[0], 4, 64);
        acc[0] += __shfl_xor(acc[0], 2, 64);
        acc[0] += __shfl_xor(acc[0], 1, 64);

        int rown = ((lane >> 5) & 1) * 4 + ((lane >> 4) & 1) * 2 + ((lane >> 3) & 1);
        if ((lane & 7) == 0 && rown < nI) {
            int i = i0 + rown;
            if (i <= j)
                Gb[tri_base(i) + (j - i)] = (float)(fabs(acc[0]) * s_invi[rown] * invj);
        }
    }
}

// ---------------- 3. greedy selection (1 wave per batch) ----------------
__global__ __launch_bounds__(64) void kselect(const float* __restrict__ G,
                                              float* __restrict__ out_a) {
    int b = blockIdx.x, lane = threadIdx.x;
    const float* Gb = G + (size_t)b * TRI;
    float best[5];
    int myidx = 0;                      // lane 0 holds selection t=0 (row 0)

    #pragma unroll
    for (int q = 0; q < 5; ++q) {       // init: sims vs row 0 -> G(0,r)=Gb[r]
        int r = lane + 64 * q;
        best[q] = (r < NN) ? Gb[r] : 3.4e38f;
    }

    int last;
    {   // argmin (first-min tie-break, matches np.argmin)
        float v = 3.5e38f; int ri = 1 << 30;
        #pragma unroll
        for (int q = 0; q < 5; ++q)
            if (best[q] < v) { v = best[q]; ri = lane + 64 * q; }
        #pragma unroll
        for (int off = 32; off >= 1; off >>= 1) {
            float ov = __shfl_xor(v, off, 64); int oi = __shfl_xor(ri, off, 64);
            if (ov < v || (ov == v && oi < ri)) { v = ov; ri = oi; }
        }
        last = ri;
    }
    if (lane == 1) myidx = last;

    for (int t = 2; t < KK; ++t) {
        #pragma unroll
        for (int q = 0; q < 5; ++q) {
            int r = lane + 64 * q;
            if (r < NN) {
                int i = min(last, r), j = max(last, r);
                best[q] = fmaxf(best[q], Gb[tri_base(i) + (j - i)]);
            }
        }
        float v = 3.5e38f; int ri = 1 << 30;
        #pragma unroll
        for (int q = 0; q < 5; ++q)
            if (best[q] < v) { v = best[q]; ri = lane + 64 * q; }
        #pragma unroll
        for (int off = 32; off >= 1; off >>= 1) {
            float ov = __shfl_xor(v, off, 64); int oi = __shfl_xor(ri, off, 64);
            if (ov < v || (ov == v && oi < ri)) { v = ov; ri = oi; }
        }
        last = ri;
        if (lane == t) myidx = last;
    }

    // stable rank-sort of the 64 indices across the wave
    int rank = 0;
    for (int j = 0; j < KK; ++j) {
        int oj = __shfl(myidx, j, 64);
        rank += (oj < myidx) || (oj == myidx && j < lane);
    }
    ((int*)(out_a + (size_t)b * KK * DA))[rank] = myidx;
}

// ---------------- 4. gather ----------------
__global__ __launch_bounds__(256) void kgather(const float* __restrict__ video,
                                               const float* __restrict__ audio,
                                               float* __restrict__ out_v,
                                               float* __restrict__ out_a) {
    int b = blockIdx.x, tid = threadIdx.x;
    __shared__ int s_idx[KK];
    const int* idxp = (const int*)(out_a + (size_t)b * KK * DA);
    if (tid < KK) s_idx[tid] = idxp[tid];
    __syncthreads();                    // idx loaded before we overwrite region

    const float4* vb4 = (const float4*)(video + (size_t)b * NN * DV);
    float4* ov4 = (float4*)(out_v + (size_t)b * KK * DV);
    #pragma unroll 4
    for (int t = tid; t < KK * DV / 4; t += 256) {
        int k = t >> 8, c = t & 255;
        ov4[t] = vb4[s_idx[k] * (DV / 4) + c];
    }
    const float4* ab4 = (const float4*)(audio + (size_t)b * NN * DA);
    float4* oa4 = (float4*)(out_a + (size_t)b * KK * DA);
    for (int t = tid; t < KK * DA / 4; t += 256) {
        int k = t >> 5, c = t & 31;
        oa4[t] = ab4[s_idx[k] * (DA / 4) + c];
    }
}

extern "C" void kernel_launch(void* const* d_in, const int* in_sizes, int n_in,
                              void* d_out, int out_size, void* d_ws, size_t ws_size,
                              hipStream_t stream) {
    const float* video = (const float*)d_in[0];
    const float* audio = (const float*)d_in[1];
    float* out   = (float*)d_out;
    float* G     = out;                               // scratch in out_v region
    double* invn = (double*)(out + NORM_OFF);         // scratch in out_v region
    float* out_v = out;
    float* out_a = out + (size_t)BB * KK * DV;

    knorm  <<<BB, 256, 0, stream>>>(video, invn);
    kgram  <<<dim3(GROUPS, BB), 256, 0, stream>>>(video, invn, G);
    kselect<<<BB, 64, 0, stream>>>(G, out_a);
    kgather<<<BB, 256, 0, stream>>>(video, audio, out_v, out_a);
}

// Round 3
// 682.015 us; speedup vs baseline: 1.9235x; 1.7521x over previous
//
#include <hip/hip_runtime.h>
#include <math.h>

// Greedy farthest-point selection via precomputed Gram triangle.
// norms -> Gram (register-tiled f64 GEMM-style, f32 LDS staging) -> greedy
// selection on G -> gather.
// Scratch inside d_out:
//   floats [0, BB*TRI)          : G triangles (23.1 MB), inside out_v region
//   floats [6,000,000, +76,800) : inv norms as f64
//   out_a + b*KK*DA             : selected indices (int bits), written by
//                                 kselect, preloaded by kgather before
//                                 overwrite.

constexpr int BB = 128, NN = 300, DV = 1024, DA = 128, KK = 64;
constexpr int TRI = NN * (NN + 1) / 2;        // 45150
constexpr int NORM_OFF = 6000000;             // float offset; > BB*TRI
constexpr int TB = 64;                        // tile edge
constexpr int NTB = (NN + TB - 1) / TB;       // 5 row-blocks
constexpr int NTILES = NTB * (NTB + 1) / 2;   // 15 upper tiles
constexpr int KC = 64;                        // K chunk
constexpr int LDP = 68;                       // padded LDS row (words)

__device__ __constant__ int c_ib[NTILES] = {0,0,0,0,0, 1,1,1,1, 2,2,2, 3,3, 4};
__device__ __constant__ int c_jb[NTILES] = {0,1,2,3,4, 1,2,3,4, 2,3,4, 3,4, 4};

__device__ __forceinline__ int tri_base(int i) { return i * NN - (i * (i - 1)) / 2; }

// ---------------- 1. inverse norms (f64) ----------------
__global__ __launch_bounds__(256) void knorm(const float* __restrict__ video,
                                             double* __restrict__ invn) {
    int b = blockIdx.x, tid = threadIdx.x, lane = tid & 63, wave = tid >> 6;
    const float* vb = video + (size_t)b * NN * DV;
    for (int r = wave; r < NN; r += 4) {
        const float* row = vb + (size_t)r * DV;
        double acc = 0.0;
        #pragma unroll
        for (int c = 0; c < 16; ++c) { float a = row[lane + 64 * c]; acc += (double)a * (double)a; }
        #pragma unroll
        for (int off = 32; off >= 1; off >>= 1) acc += __shfl_xor(acc, off, 64);
        if (lane == 0) invn[b * NN + r] = 1.0 / (sqrt(acc) + 1e-5);
    }
}

// ---------------- 2. Gram triangle, register-tiled ----------------
// Block = (tile, batch). 256 threads as 16x16; each computes a 4x4 f64 tile.
// LDS holds f32 k-major slabs As[k][i], Bs[k][j]; converts are in-register
// (f32*f32 in f64 FMA is exact -> identical numerics to R2's f64 path).
__global__ __launch_bounds__(256, 4) void kgram(const float* __restrict__ video,
                                                const double* __restrict__ invn,
                                                float* __restrict__ G) {
    const int tile = blockIdx.x, b = blockIdx.y;
    const int i0 = c_ib[tile] * TB, j0 = c_jb[tile] * TB;
    const int tid = threadIdx.x;
    const int tx = tid & 15, ty = tid >> 4;

    __shared__ float As[KC][LDP];
    __shared__ float Bs[KC][LDP];
    __shared__ double s_invi[TB], s_invj[TB];

    const float* vb = video + (size_t)b * NN * DV;
    const double* invb = invn + b * NN;

    if (tid < TB)       s_invi[tid] = (i0 + tid < NN) ? invb[i0 + tid] : 0.0;
    else if (tid < 2*TB) { int t = tid - TB; s_invj[t] = (j0 + t < NN) ? invb[j0 + t] : 0.0; }

    double acc[4][4];
    #pragma unroll
    for (int r = 0; r < 4; ++r)
        #pragma unroll
        for (int c = 0; c < 4; ++c) acc[r][c] = 0.0;

    const int srow = tid >> 2;        // 0..63: staged row within tile
    const int sqb  = tid & 3;         // quad base
    const int gi = i0 + srow, gj = j0 + srow;
    const float4 z4 = make_float4(0.f, 0.f, 0.f, 0.f);

    for (int kc = 0; kc < DV / KC; ++kc) {
        const int k0 = kc * KC;
        __syncthreads();              // previous chunk fully consumed
        #pragma unroll
        for (int q = 0; q < 4; ++q) {
            int quad = sqb + q * 4;                   // 0..15
            int kk = quad * 4;
            float4 va = (gi < NN) ? *(const float4*)(vb + (size_t)gi * DV + k0 + kk) : z4;
            As[kk + 0][srow] = va.x; As[kk + 1][srow] = va.y;
            As[kk + 2][srow] = va.z; As[kk + 3][srow] = va.w;
            float4 vbj = (gj < NN) ? *(const float4*)(vb + (size_t)gj * DV + k0 + kk) : z4;
            Bs[kk + 0][srow] = vbj.x; Bs[kk + 1][srow] = vbj.y;
            Bs[kk + 2][srow] = vbj.z; Bs[kk + 3][srow] = vbj.w;
        }
        __syncthreads();

        #pragma unroll 4
        for (int kk = 0; kk < KC; ++kk) {
            float4 a4 = *(const float4*)&As[kk][ty * 4];
            float4 b4 = *(const float4*)&Bs[kk][tx * 4];
            double ad[4] = {(double)a4.x, (double)a4.y, (double)a4.z, (double)a4.w};
            double bd[4] = {(double)b4.x, (double)b4.y, (double)b4.z, (double)b4.w};
            #pragma unroll
            for (int r = 0; r < 4; ++r)
                #pragma unroll
                for (int c = 0; c < 4; ++c)
                    acc[r][c] = fma(ad[r], bd[c], acc[r][c]);
        }
    }

    float* Gb = G + (size_t)b * TRI;
    #pragma unroll
    for (int r = 0; r < 4; ++r) {
        int i = i0 + ty * 4 + r;
        #pragma unroll
        for (int c = 0; c < 4; ++c) {
            int j = j0 + tx * 4 + c;
            if (i <= j && j < NN)
                Gb[tri_base(i) + (j - i)] =
                    (float)(fabs(acc[r][c]) * s_invi[ty * 4 + r] * s_invj[tx * 4 + c]);
        }
    }
}

// ---------------- 3. greedy selection (1 wave per batch) ----------------
__global__ __launch_bounds__(64) void kselect(const float* __restrict__ G,
                                              float* __restrict__ out_a) {
    int b = blockIdx.x, lane = threadIdx.x;
    const float* Gb = G + (size_t)b * TRI;
    float best[5];
    int myidx = 0;

    #pragma unroll
    for (int q = 0; q < 5; ++q) {
        int r = lane + 64 * q;
        best[q] = (r < NN) ? Gb[r] : 3.4e38f;
    }

    int last;
    {
        float v = 3.5e38f; int ri = 1 << 30;
        #pragma unroll
        for (int q = 0; q < 5; ++q)
            if (best[q] < v) { v = best[q]; ri = lane + 64 * q; }
        #pragma unroll
        for (int off = 32; off >= 1; off >>= 1) {
            float ov = __shfl_xor(v, off, 64); int oi = __shfl_xor(ri, off, 64);
            if (ov < v || (ov == v && oi < ri)) { v = ov; ri = oi; }
        }
        last = ri;
    }
    if (lane == 1) myidx = last;

    for (int t = 2; t < KK; ++t) {
        #pragma unroll
        for (int q = 0; q < 5; ++q) {
            int r = lane + 64 * q;
            if (r < NN) {
                int i = min(last, r), j = max(last, r);
                best[q] = fmaxf(best[q], Gb[tri_base(i) + (j - i)]);
            }
        }
        float v = 3.5e38f; int ri = 1 << 30;
        #pragma unroll
        for (int q = 0; q < 5; ++q)
            if (best[q] < v) { v = best[q]; ri = lane + 64 * q; }
        #pragma unroll
        for (int off = 32; off >= 1; off >>= 1) {
            float ov = __shfl_xor(v, off, 64); int oi = __shfl_xor(ri, off, 64);
            if (ov < v || (ov == v && oi < ri)) { v = ov; ri = oi; }
        }
        last = ri;
        if (lane == t) myidx = last;
    }

    int rank = 0;
    for (int j = 0; j < KK; ++j) {
        int oj = __shfl(myidx, j, 64);
        rank += (oj < myidx) || (oj == myidx && j < lane);
    }
    ((int*)(out_a + (size_t)b * KK * DA))[rank] = myidx;
}

// ---------------- 4. gather ----------------
__global__ __launch_bounds__(256) void kgather(const float* __restrict__ video,
                                               const float* __restrict__ audio,
                                               float* __restrict__ out_v,
                                               float* __restrict__ out_a) {
    int b = blockIdx.x, tid = threadIdx.x;
    __shared__ int s_idx[KK];
    const int* idxp = (const int*)(out_a + (size_t)b * KK * DA);
    if (tid < KK) s_idx[tid] = idxp[tid];
    __syncthreads();

    const float4* vb4 = (const float4*)(video + (size_t)b * NN * DV);
    float4* ov4 = (float4*)(out_v + (size_t)b * KK * DV);
    #pragma unroll 4
    for (int t = tid; t < KK * DV / 4; t += 256) {
        int k = t >> 8, c = t & 255;
        ov4[t] = vb4[s_idx[k] * (DV / 4) + c];
    }
    const float4* ab4 = (const float4*)(audio + (size_t)b * NN * DA);
    float4* oa4 = (float4*)(out_a + (size_t)b * KK * DA);
    for (int t = tid; t < KK * DA / 4; t += 256) {
        int k = t >> 5, c = t & 31;
        oa4[t] = ab4[s_idx[k] * (DA / 4) + c];
    }
}

extern "C" void kernel_launch(void* const* d_in, const int* in_sizes, int n_in,
                              void* d_out, int out_size, void* d_ws, size_t ws_size,
                              hipStream_t stream) {
    const float* video = (const float*)d_in[0];
    const float* audio = (const float*)d_in[1];
    float* out   = (float*)d_out;
    float* G     = out;
    double* invn = (double*)(out + NORM_OFF);
    float* out_v = out;
    float* out_a = out + (size_t)BB * KK * DV;

    knorm  <<<BB, 256, 0, stream>>>(video, invn);
    kgram  <<<dim3(NTILES, BB), 256, 0, stream>>>(video, invn, G);
    kselect<<<BB, 64, 0, stream>>>(G, out_a);
    kgather<<<BB, 256, 0, stream>>>(video, audio, out_v, out_a);
}

// Round 4
// 572.359 us; speedup vs baseline: 2.2920x; 1.1916x over previous
//
#include <hip/hip_runtime.h>
#include <math.h>

// Greedy farthest-point selection via precomputed Gram triangle.
// kgram (norm-fused, f32 FMA + f64 chunk-master accum) -> kselect -> kgather.
// Numerics: f32 products accumulated in f32 within KC=64 chunks, chunk sums
// accumulated in f64 -> |cos| error ~3e-7, 4x below np-sgemm's own error.
// Scratch inside d_out:
//   floats [0, BB*TRI)  : G triangles (23.1 MB) in out_v region
//   out_a + b*KK*DA     : selected indices (int bits) per batch, written by
//                         kselect, consumed+overwritten by kgather block b.

constexpr int BB = 128, NN = 300, DV = 1024, DA = 128, KK = 64;
constexpr int TRI = NN * (NN + 1) / 2;        // 45150
constexpr int TB = 64;
constexpr int NTB = (NN + TB - 1) / TB;       // 5
constexpr int NTILES = NTB * (NTB + 1) / 2;   // 15
constexpr int KC = 64;
constexpr int LDP = 68;                       // padded LDS row (words)

__device__ __constant__ int c_ib[NTILES] = {0,0,0,0,0, 1,1,1,1, 2,2,2, 3,3, 4};
__device__ __constant__ int c_jb[NTILES] = {0,1,2,3,4, 1,2,3,4, 2,3,4, 3,4, 4};

__device__ __forceinline__ int tri_base(int i) { return i * NN - (i * (i - 1)) / 2; }

// ---------------- 1. Gram triangle (norms fused) ----------------
// Block = (tile, batch), 256 threads as 16x16, each a 4x4 tile.
// f32 LDS k-major slabs; norms accumulated during staging.
__global__ __launch_bounds__(256, 4) void kgram(const float* __restrict__ video,
                                                float* __restrict__ G) {
    const int tile = blockIdx.x, b = blockIdx.y;
    const int i0 = c_ib[tile] * TB, j0 = c_jb[tile] * TB;
    const int tid = threadIdx.x;
    const int tx = tid & 15, ty = tid >> 4;

    __shared__ float  As[KC][LDP];
    __shared__ float  Bs[KC][LDP];
    __shared__ double s_red[2][TB][4];
    __shared__ double s_invi[TB], s_invj[TB];

    const float* vb = video + (size_t)b * NN * DV;

    float  acc[4][4];
    double accd[4][4];
    #pragma unroll
    for (int r = 0; r < 4; ++r)
        #pragma unroll
        for (int c = 0; c < 4; ++c) { acc[r][c] = 0.f; accd[r][c] = 0.0; }

    const int srow = tid >> 2;        // 0..63
    const int sqb  = tid & 3;
    const int gi = i0 + srow, gj = j0 + srow;
    const float4 z4 = make_float4(0.f, 0.f, 0.f, 0.f);
    double nrmi = 0.0, nrmj = 0.0;

    for (int kc = 0; kc < DV / KC; ++kc) {
        const int k0 = kc * KC;
        __syncthreads();              // previous chunk fully consumed
        float ni = 0.f, nj = 0.f;
        #pragma unroll
        for (int q = 0; q < 4; ++q) {
            int kk = (sqb + q * 4) * 4;
            float4 va = (gi < NN) ? *(const float4*)(vb + (size_t)gi * DV + k0 + kk) : z4;
            As[kk + 0][srow] = va.x; As[kk + 1][srow] = va.y;
            As[kk + 2][srow] = va.z; As[kk + 3][srow] = va.w;
            ni = fmaf(va.x, va.x, ni); ni = fmaf(va.y, va.y, ni);
            ni = fmaf(va.z, va.z, ni); ni = fmaf(va.w, va.w, ni);
            float4 vbj = (gj < NN) ? *(const float4*)(vb + (size_t)gj * DV + k0 + kk) : z4;
            Bs[kk + 0][srow] = vbj.x; Bs[kk + 1][srow] = vbj.y;
            Bs[kk + 2][srow] = vbj.z; Bs[kk + 3][srow] = vbj.w;
            nj = fmaf(vbj.x, vbj.x, nj); nj = fmaf(vbj.y, vbj.y, nj);
            nj = fmaf(vbj.z, vbj.z, nj); nj = fmaf(vbj.w, vbj.w, nj);
        }
        nrmi += (double)ni; nrmj += (double)nj;
        __syncthreads();

        #pragma unroll 8
        for (int kk = 0; kk < KC; ++kk) {
            float4 a4 = *(const float4*)&As[kk][ty * 4];
            float4 b4 = *(const float4*)&Bs[kk][tx * 4];
            float av[4] = {a4.x, a4.y, a4.z, a4.w};
            float bv[4] = {b4.x, b4.y, b4.z, b4.w};
            #pragma unroll
            for (int r = 0; r < 4; ++r)
                #pragma unroll
                for (int c = 0; c < 4; ++c)
                    acc[r][c] = fmaf(av[r], bv[c], acc[r][c]);
        }
        // fold chunk into f64 master
        #pragma unroll
        for (int r = 0; r < 4; ++r)
            #pragma unroll
            for (int c = 0; c < 4; ++c) { accd[r][c] += (double)acc[r][c]; acc[r][c] = 0.f; }
    }

    // reduce norm partials (4 stagers per row) -> inv norms
    s_red[0][srow][sqb] = nrmi;
    s_red[1][srow][sqb] = nrmj;
    __syncthreads();
    if (tid < TB) {
        double s = s_red[0][tid][0] + s_red[0][tid][1] + s_red[0][tid][2] + s_red[0][tid][3];
        s_invi[tid] = 1.0 / (sqrt(s) + 1e-5);
    } else if (tid < 2 * TB) {
        int t = tid - TB;
        double s = s_red[1][t][0] + s_red[1][t][1] + s_red[1][t][2] + s_red[1][t][3];
        s_invj[t] = 1.0 / (sqrt(s) + 1e-5);
    }
    __syncthreads();

    float* Gb = G + (size_t)b * TRI;
    #pragma unroll
    for (int r = 0; r < 4; ++r) {
        int i = i0 + ty * 4 + r;
        #pragma unroll
        for (int c = 0; c < 4; ++c) {
            int j = j0 + tx * 4 + c;
            if (i <= j && j < NN)
                Gb[tri_base(i) + (j - i)] =
                    (float)(fabs(accd[r][c]) * s_invi[ty * 4 + r] * s_invj[tx * 4 + c]);
        }
    }
}

// ---------------- 2. greedy selection (1 wave per batch) ----------------
__global__ __launch_bounds__(64) void kselect(const float* __restrict__ G,
                                              float* __restrict__ out_a) {
    int b = blockIdx.x, lane = threadIdx.x;
    const float* Gb = G + (size_t)b * TRI;
    float best[5];
    int myidx = 0;

    #pragma unroll
    for (int q = 0; q < 5; ++q) {
        int r = lane + 64 * q;
        best[q] = (r < NN) ? Gb[r] : 3.4e38f;
    }

    int last;
    {
        float v = 3.5e38f; int ri = 1 << 30;
        #pragma unroll
        for (int q = 0; q < 5; ++q)
            if (best[q] < v) { v = best[q]; ri = lane + 64 * q; }
        #pragma unroll
        for (int off = 32; off >= 1; off >>= 1) {
            float ov = __shfl_xor(v, off, 64); int oi = __shfl_xor(ri, off, 64);
            if (ov < v || (ov == v && oi < ri)) { v = ov; ri = oi; }
        }
        last = ri;
    }
    if (lane == 1) myidx = last;

    for (int t = 2; t < KK; ++t) {
        #pragma unroll
        for (int q = 0; q < 5; ++q) {
            int r = lane + 64 * q;
            if (r < NN) {
                int i = min(last, r), j = max(last, r);
                best[q] = fmaxf(best[q], Gb[tri_base(i) + (j - i)]);
            }
        }
        float v = 3.5e38f; int ri = 1 << 30;
        #pragma unroll
        for (int q = 0; q < 5; ++q)
            if (best[q] < v) { v = best[q]; ri = lane + 64 * q; }
        #pragma unroll
        for (int off = 32; off >= 1; off >>= 1) {
            float ov = __shfl_xor(v, off, 64); int oi = __shfl_xor(ri, off, 64);
            if (ov < v || (ov == v && oi < ri)) { v = ov; ri = oi; }
        }
        last = ri;
        if (lane == t) myidx = last;
    }

    int rank = 0;
    for (int j = 0; j < KK; ++j) {
        int oj = __shfl(myidx, j, 64);
        rank += (oj < myidx) || (oj == myidx && j < lane);
    }
    ((int*)(out_a + (size_t)b * KK * DA))[rank] = myidx;
}

// ---------------- 3. gather ----------------
__global__ __launch_bounds__(256) void kgather(const float* __restrict__ video,
                                               const float* __restrict__ audio,
                                               float* __restrict__ out_v,
                                               float* __restrict__ out_a) {
    int b = blockIdx.x, tid = threadIdx.x;
    __shared__ int s_idx[KK];
    const int* idxp = (const int*)(out_a + (size_t)b * KK * DA);
    if (tid < KK) s_idx[tid] = idxp[tid];
    __syncthreads();

    const float4* vb4 = (const float4*)(video + (size_t)b * NN * DV);
    float4* ov4 = (float4*)(out_v + (size_t)b * KK * DV);
    #pragma unroll 4
    for (int t = tid; t < KK * DV / 4; t += 256) {
        int k = t >> 8, c = t & 255;
        ov4[t] = vb4[s_idx[k] * (DV / 4) + c];
    }
    const float4* ab4 = (const float4*)(audio + (size_t)b * NN * DA);
    float4* oa4 = (float4*)(out_a + (size_t)b * KK * DA);
    for (int t = tid; t < KK * DA / 4; t += 256) {
        int k = t >> 5, c = t & 31;
        oa4[t] = ab4[s_idx[k] * (DA / 4) + c];
    }
}

extern "C" void kernel_launch(void* const* d_in, const int* in_sizes, int n_in,
                              void* d_out, int out_size, void* d_ws, size_t ws_size,
                              hipStream_t stream) {
    const float* video = (const float*)d_in[0];
    const float* audio = (const float*)d_in[1];
    float* out   = (float*)d_out;
    float* G     = out;
    float* out_v = out;
    float* out_a = out + (size_t)BB * KK * DV;

    kgram  <<<dim3(NTILES, BB), 256, 0, stream>>>(video, G);
    kselect<<<BB, 64, 0, stream>>>(G, out_a);
    kgather<<<BB, 256, 0, stream>>>(video, audio, out_v, out_a);
}

// Round 5
// 341.062 us; speedup vs baseline: 3.8464x; 1.6782x over previous
//
#include <hip/hip_runtime.h>
#include <math.h>

// Greedy farthest-point selection via precomputed Gram triangle.
// kgram: MFMA f16 2-way-split (exact split, 4 cross-products, f32 accum;
//        |cos| error ~5e-7, far below argmin decision margins)
// kselect: greedy argmin on G; kgather: final gather.
// Scratch inside d_out:
//   floats [0, BB*TRI)  : G triangles (23.1 MB) in out_v region
//   out_a + b*KK*DA     : selected indices (int bits), kselect->kgather.

constexpr int BB = 128, NN = 300, DV = 1024, DA = 128, KK = 64;
constexpr int TRI = NN * (NN + 1) / 2;        // 45150
constexpr int TB = 64;
constexpr int NTILES = 15;                    // upper-tri 64x64 tiles of 300x300
constexpr int KC = 64;                        // K chunk
constexpr int LDH = 68;                       // f16 LDS row stride (136 B, 8B-aligned)

__device__ __constant__ int c_ib[NTILES] = {0,0,0,0,0, 1,1,1,1, 2,2,2, 3,3, 4};
__device__ __constant__ int c_jb[NTILES] = {0,1,2,3,4, 1,2,3,4, 2,3,4, 3,4, 4};

typedef _Float16 f16x8 __attribute__((ext_vector_type(8)));
typedef float    f32x4 __attribute__((ext_vector_type(4)));

union H4 { _Float16 h[4]; uint2 u; };
union F8 { uint2 u2[2]; f16x8 v; };

__device__ __forceinline__ int tri_base(int i) { return i * NN - (i * (i - 1)) / 2; }

// ---------------- 1. Gram triangle via f16-split MFMA ----------------
// Grid 1920 = 15 tiles x 128 batches, XCD-swizzled so each XCD owns 16
// whole batches (keeps the 1.2 MB/batch row data L2-resident).
// Block: 256 threads = 4 waves; wave w computes the 32x32 quadrant
// (wr=w>>1, wc=w&1) of the 64x64 tile as 2x2 MFMA fragments.
// Numerics: x=x1+x2 exact f16 split; acc += x1y1+x1y2+x2y1+x2y2 (all four,
// so only the ~2^-22 split residual + f32 MFMA accum rounding remain).
// A/B fragments use the SAME (group,elem)->k map, so any k-permutation
// error cancels; C/D map is the m89-verified one.
__global__ __launch_bounds__(256) void kgram(const float* __restrict__ video,
                                             float* __restrict__ G) {
    const int bid  = blockIdx.x;
    const int swz  = (bid & 7) * 240 + (bid >> 3);      // bijective: 1920=8*240
    const int batch = swz / 15;
    const int tile  = swz - batch * 15;
    const int i0 = c_ib[tile] * TB, j0 = c_jb[tile] * TB;
    const int tid = threadIdx.x;

    __shared__ _Float16 sH[4][TB][LDH];   // [A1,A2,B1,B2][row][k]  ~34.8 KB
    __shared__ float    s_part[256];
    __shared__ double   s_inv[2][TB];

    const float* vb = video + (size_t)batch * NN * DV;

    // staging role: thread -> (slab, row, k-half)
    const int slab  = tid >> 7;           // 0=A(i-rows), 1=B(j-rows)
    const int lrow  = (tid >> 1) & 63;
    const int khalf = tid & 1;
    const int grow  = (slab ? j0 : i0) + lrow;
    const bool rok  = grow < NN;
    const float* srcbase = vb + (size_t)(rok ? grow : 0) * DV + khalf * 32;

    // compute role
    const int lane = tid & 63, w = tid >> 6;
    const int wr = w >> 1, wc = w & 1;
    const int g = lane >> 4, c16 = lane & 15;

    f32x4 acc[2][2];
    #pragma unroll
    for (int fr = 0; fr < 2; ++fr)
        #pragma unroll
        for (int fc = 0; fc < 2; ++fc) acc[fr][fc] = (f32x4){0.f, 0.f, 0.f, 0.f};

    float ps = 0.f;                        // norm partial (this thread's slice)

    for (int kc = 0; kc < DV / KC; ++kc) {
        __syncthreads();                   // previous chunk fully consumed
        const float4* src = (const float4*)(srcbase + kc * KC);
        #pragma unroll
        for (int q = 0; q < 8; ++q) {
            float4 v = rok ? src[q] : make_float4(0.f, 0.f, 0.f, 0.f);
            ps = fmaf(v.x, v.x, fmaf(v.y, v.y, fmaf(v.z, v.z, fmaf(v.w, v.w, ps))));
            float comp[4] = {v.x, v.y, v.z, v.w};
            H4 hi, lo;
            #pragma unroll
            for (int c = 0; c < 4; ++c) {
                _Float16 h1 = (_Float16)comp[c];
                float r = comp[c] - (float)h1;   // exact (Sterbenz)
                hi.h[c] = h1;
                lo.h[c] = (_Float16)r;
            }
            const int kl = khalf * 32 + q * 4;
            *(uint2*)&sH[slab * 2 + 0][lrow][kl] = hi.u;
            *(uint2*)&sH[slab * 2 + 1][lrow][kl] = lo.u;
        }
        __syncthreads();

        #pragma unroll
        for (int s = 0; s < 2; ++s) {      // two K=32 steps per chunk
            f16x8 Af[2][2], Bf[2][2];      // [frag][split]
            #pragma unroll
            for (int fr = 0; fr < 2; ++fr) {
                const int row = 32 * wr + 16 * fr + c16;
                #pragma unroll
                for (int p = 0; p < 2; ++p) {
                    F8 t8;
                    t8.u2[0] = *(const uint2*)&sH[p][row][s * 32 + 4 * g];
                    t8.u2[1] = *(const uint2*)&sH[p][row][s * 32 + 16 + 4 * g];
                    Af[fr][p] = t8.v;
                }
            }
            #pragma unroll
            for (int fc = 0; fc < 2; ++fc) {
                const int row = 32 * wc + 16 * fc + c16;
                #pragma unroll
                for (int p = 0; p < 2; ++p) {
                    F8 t8;
                    t8.u2[0] = *(const uint2*)&sH[2 + p][row][s * 32 + 4 * g];
                    t8.u2[1] = *(const uint2*)&sH[2 + p][row][s * 32 + 16 + 4 * g];
                    Bf[fc][p] = t8.v;
                }
            }
            #pragma unroll
            for (int fr = 0; fr < 2; ++fr)
                #pragma unroll
                for (int fc = 0; fc < 2; ++fc) {
                    acc[fr][fc] = __builtin_amdgcn_mfma_f32_16x16x32_f16(Af[fr][0], Bf[fc][0], acc[fr][fc], 0, 0, 0);
                    acc[fr][fc] = __builtin_amdgcn_mfma_f32_16x16x32_f16(Af[fr][0], Bf[fc][1], acc[fr][fc], 0, 0, 0);
                    acc[fr][fc] = __builtin_amdgcn_mfma_f32_16x16x32_f16(Af[fr][1], Bf[fc][0], acc[fr][fc], 0, 0, 0);
                    acc[fr][fc] = __builtin_amdgcn_mfma_f32_16x16x32_f16(Af[fr][1], Bf[fc][1], acc[fr][fc], 0, 0, 0);
                }
        }
    }

    // norms: reduce the two k-half partials per (slab,row)
    s_part[tid] = ps;
    __syncthreads();
    if (tid < 128) {
        float ssum = s_part[2 * tid] + s_part[2 * tid + 1];
        s_inv[tid >> 6][tid & 63] = 1.0 / (sqrt((double)ssum) + 1e-5);
    }
    __syncthreads();

    float* Gb = G + (size_t)batch * TRI;
    #pragma unroll
    for (int fr = 0; fr < 2; ++fr)
        #pragma unroll
        for (int fc = 0; fc < 2; ++fc)
            #pragma unroll
            for (int reg = 0; reg < 4; ++reg) {
                const int il = 32 * wr + 16 * fr + 4 * g + reg;   // D row (m89)
                const int jl = 32 * wc + 16 * fc + c16;           // D col (m89)
                const int i = i0 + il, j = j0 + jl;
                if (i <= j && j < NN)
                    Gb[tri_base(i) + (j - i)] =
                        (float)(fabs((double)acc[fr][fc][reg]) * s_inv[0][il] * s_inv[1][jl]);
            }
}

// ---------------- 2. greedy selection (1 wave per batch) ----------------
__global__ __launch_bounds__(64) void kselect(const float* __restrict__ G,
                                              float* __restrict__ out_a) {
    int b = blockIdx.x, lane = threadIdx.x;
    const float* Gb = G + (size_t)b * TRI;
    float best[5];
    int myidx = 0;

    #pragma unroll
    for (int q = 0; q < 5; ++q) {
        int r = lane + 64 * q;
        best[q] = (r < NN) ? Gb[r] : 3.4e38f;
    }

    int last;
    {
        float v = 3.5e38f; int ri = 1 << 30;
        #pragma unroll
        for (int q = 0; q < 5; ++q)
            if (best[q] < v) { v = best[q]; ri = lane + 64 * q; }
        #pragma unroll
        for (int off = 32; off >= 1; off >>= 1) {
            float ov = __shfl_xor(v, off, 64); int oi = __shfl_xor(ri, off, 64);
            if (ov < v || (ov == v && oi < ri)) { v = ov; ri = oi; }
        }
        last = ri;
    }
    if (lane == 1) myidx = last;

    for (int t = 2; t < KK; ++t) {
        #pragma unroll
        for (int q = 0; q < 5; ++q) {
            int r = lane + 64 * q;
            if (r < NN) {
                int i = min(last, r), j = max(last, r);
                best[q] = fmaxf(best[q], Gb[tri_base(i) + (j - i)]);
            }
        }
        float v = 3.5e38f; int ri = 1 << 30;
        #pragma unroll
        for (int q = 0; q < 5; ++q)
            if (best[q] < v) { v = best[q]; ri = lane + 64 * q; }
        #pragma unroll
        for (int off = 32; off >= 1; off >>= 1) {
            float ov = __shfl_xor(v, off, 64); int oi = __shfl_xor(ri, off, 64);
            if (ov < v || (ov == v && oi < ri)) { v = ov; ri = oi; }
        }
        last = ri;
        if (lane == t) myidx = last;
    }

    int rank = 0;
    for (int j = 0; j < KK; ++j) {
        int oj = __shfl(myidx, j, 64);
        rank += (oj < myidx) || (oj == myidx && j < lane);
    }
    ((int*)(out_a + (size_t)b * KK * DA))[rank] = myidx;
}

// ---------------- 3. gather ----------------
__global__ __launch_bounds__(256) void kgather(const float* __restrict__ video,
                                               const float* __restrict__ audio,
                                               float* __restrict__ out_v,
                                               float* __restrict__ out_a) {
    int b = blockIdx.x, tid = threadIdx.x;
    __shared__ int s_idx[KK];
    const int* idxp = (const int*)(out_a + (size_t)b * KK * DA);
    if (tid < KK) s_idx[tid] = idxp[tid];
    __syncthreads();

    const float4* vb4 = (const float4*)(video + (size_t)b * NN * DV);
    float4* ov4 = (float4*)(out_v + (size_t)b * KK * DV);
    #pragma unroll 4
    for (int t = tid; t < KK * DV / 4; t += 256) {
        int k = t >> 8, c = t & 255;
        ov4[t] = vb4[s_idx[k] * (DV / 4) + c];
    }
    const float4* ab4 = (const float4*)(audio + (size_t)b * NN * DA);
    float4* oa4 = (float4*)(out_a + (size_t)b * KK * DA);
    for (int t = tid; t < KK * DA / 4; t += 256) {
        int k = t >> 5, c = t & 31;
        oa4[t] = ab4[s_idx[k] * (DA / 4) + c];
    }
}

extern "C" void kernel_launch(void* const* d_in, const int* in_sizes, int n_in,
                              void* d_out, int out_size, void* d_ws, size_t ws_size,
                              hipStream_t stream) {
    const float* video = (const float*)d_in[0];
    const float* audio = (const float*)d_in[1];
    float* out   = (float*)d_out;
    float* G     = out;
    float* out_v = out;
    float* out_a = out + (size_t)BB * KK * DV;

    kgram  <<<NTILES * BB, 256, 0, stream>>>(video, G);
    kselect<<<BB, 64, 0, stream>>>(G, out_a);
    kgather<<<BB, 256, 0, stream>>>(video, audio, out_v, out_a);
}

// Round 8
// 314.920 us; speedup vs baseline: 4.1657x; 1.0830x over previous
//
#include <hip/hip_runtime.h>
#include <math.h>

// Greedy farthest-point selection via precomputed Gram triangle.
// kgram: MFMA f16 2-way-split (RNE hi + RNE lo residual, 3 cross-products,
//        f32 accum), software-pipelined staging, permuted-k LDS for
//        single-b128 fragment loads.
// kfused: greedy argmin on G (wave 0) + gather (all waves), one block/batch.
// G scratch lives in d_ws (23.1 MB) -> no overlap between kfused's G reads
// and its out_v writes (the R7 failure was exactly that race: G in out_v
// region, fused gather overwrote other blocks' unread triangles).
// Fallback if ws_size < needed: R5-proven 3-kernel path (G in out_v, separate
// kselect -> kgather with idx staged through out_a).

constexpr int BB = 128, NN = 300, DV = 1024, DA = 128, KK = 64;
constexpr int TRI = NN * (NN + 1) / 2;        // 45150
constexpr int TB = 64;
constexpr int NTILES = 15;                    // upper-tri 64x64 tiles of 300x300
constexpr int LDH = 72;                       // f16 row stride: 144 B, 16B-aligned

__device__ __constant__ int c_ib[NTILES] = {0,0,0,0,0, 1,1,1,1, 2,2,2, 3,3, 4};
__device__ __constant__ int c_jb[NTILES] = {0,1,2,3,4, 1,2,3,4, 2,3,4, 3,4, 4};

typedef _Float16 f16x8 __attribute__((ext_vector_type(8)));
typedef float    f32x4 __attribute__((ext_vector_type(4)));

union H4 { _Float16 h[4]; uint2 u; };

__device__ __forceinline__ int tri_base(int i) { return i * NN - (i * (i - 1)) / 2; }

// ---------------- 1. Gram triangle via f16-split MFMA ----------------
__global__ __launch_bounds__(256) void kgram(const float* __restrict__ video,
                                             float* __restrict__ G) {
    const int bid  = blockIdx.x;
    const int swz  = (bid & 7) * 240 + (bid >> 3);      // bijective: 1920=8*240
    const int batch = swz / 15;
    const int tile  = swz - batch * 15;
    const int i0 = c_ib[tile] * TB, j0 = c_jb[tile] * TB;
    const bool diag = (i0 == j0);
    const int tid = threadIdx.x;

    __shared__ _Float16 sH[4][TB][LDH];   // [A-hi,A-lo,B-hi,B-lo] 36.9 KB
    __shared__ float    s_part[256];
    __shared__ double   s_inv[2][TB];

    const float* vb = video + (size_t)batch * NN * DV;

    // staging role
    const int slab  = tid >> 7;           // 0=A(i-rows), 1=B(j-rows)
    const int lrow  = (tid >> 1) & 63;
    const int khalf = tid & 1;
    const int grow  = (slab ? j0 : i0) + lrow;
    const bool rok  = grow < NN;
    const bool stage_on = !(diag && slab == 1);   // diag: B slab = A slab
    const float4* srcb4 = (const float4*)(vb + (size_t)(rok ? grow : 0) * DV + khalf * 32);

    // compute role
    const int lane = tid & 63, w = tid >> 6;
    const int wr = w >> 1, wc = w & 1;
    const int g = lane >> 4, c16 = lane & 15;
    const int bplane = diag ? 0 : 2;

    f32x4 acc[2][2];
    #pragma unroll
    for (int fr = 0; fr < 2; ++fr)
        #pragma unroll
        for (int fc = 0; fc < 2; ++fc) acc[fr][fc] = (f32x4){0.f, 0.f, 0.f, 0.f};

    float ps = 0.f;
    float4 ld[8];
    const float4 z4 = make_float4(0.f, 0.f, 0.f, 0.f);

    if (stage_on) {
        #pragma unroll
        for (int q = 0; q < 8; ++q) ld[q] = rok ? srcb4[q] : z4;
    }

    for (int kc = 0; kc < 16; ++kc) {
        // ---- stage current chunk from regs (cvt + LDS write) ----
        if (stage_on) {
            #pragma unroll
            for (int q = 0; q < 8; ++q) {
                float4 v = ld[q];
                ps = fmaf(v.x, v.x, fmaf(v.y, v.y, fmaf(v.z, v.z, fmaf(v.w, v.w, ps))));
                H4 hi, lo;
                {
                    _Float16 h0 = (_Float16)v.x, h1 = (_Float16)v.y,
                             h2 = (_Float16)v.z, h3 = (_Float16)v.w;
                    hi.h[0] = h0; hi.h[1] = h1; hi.h[2] = h2; hi.h[3] = h3;
                    lo.h[0] = (_Float16)(v.x - (float)h0);
                    lo.h[1] = (_Float16)(v.y - (float)h1);
                    lo.h[2] = (_Float16)(v.z - (float)h2);
                    lo.h[3] = (_Float16)(v.w - (float)h3);
                }
                const int pbase = khalf * 32 + 8 * (q & 3) + 4 * (q >> 2);
                *(uint2*)&sH[slab * 2 + 0][lrow][pbase] = hi.u;
                *(uint2*)&sH[slab * 2 + 1][lrow][pbase] = lo.u;
            }
        }
        __syncthreads();

        // ---- prefetch next chunk (latency hides under MFMA below) ----
        if (kc < 15 && stage_on) {
            #pragma unroll
            for (int q = 0; q < 8; ++q) ld[q] = rok ? srcb4[(kc + 1) * 16 + q] : z4;
        }

        // ---- compute ----
        #pragma unroll
        for (int s = 0; s < 2; ++s) {
            f16x8 Ah[2], Al[2], Bh[2], Bl[2];
            #pragma unroll
            for (int fr = 0; fr < 2; ++fr) {
                const int row = 32 * wr + 16 * fr + c16;
                Ah[fr] = *(const f16x8*)&sH[0][row][s * 32 + 8 * g];
                Al[fr] = *(const f16x8*)&sH[1][row][s * 32 + 8 * g];
            }
            #pragma unroll
            for (int fc = 0; fc < 2; ++fc) {
                const int row = 32 * wc + 16 * fc + c16;
                Bh[fc] = *(const f16x8*)&sH[bplane + 0][row][s * 32 + 8 * g];
                Bl[fc] = *(const f16x8*)&sH[bplane + 1][row][s * 32 + 8 * g];
            }
            #pragma unroll
            for (int fr = 0; fr < 2; ++fr)
                #pragma unroll
                for (int fc = 0; fc < 2; ++fc) {
                    acc[fr][fc] = __builtin_amdgcn_mfma_f32_16x16x32_f16(Ah[fr], Bh[fc], acc[fr][fc], 0, 0, 0);
                    acc[fr][fc] = __builtin_amdgcn_mfma_f32_16x16x32_f16(Ah[fr], Bl[fc], acc[fr][fc], 0, 0, 0);
                    acc[fr][fc] = __builtin_amdgcn_mfma_f32_16x16x32_f16(Al[fr], Bh[fc], acc[fr][fc], 0, 0, 0);
                }
        }
        __syncthreads();
    }

    // ---- norms ----
    s_part[tid] = ps;
    __syncthreads();
    if (tid < 128) {
        const int st = tid >> 6, r = tid & 63;
        const int src = (st && !diag) ? 128 + 2 * r : 2 * r;   // diag: reuse A partials
        float ssum = s_part[src] + s_part[src + 1];
        s_inv[st][r] = 1.0 / (sqrt((double)ssum) + 1e-5);
    }
    __syncthreads();

    float* Gb = G + (size_t)batch * TRI;
    #pragma unroll
    for (int fr = 0; fr < 2; ++fr)
        #pragma unroll
        for (int fc = 0; fc < 2; ++fc)
            #pragma unroll
            for (int reg = 0; reg < 4; ++reg) {
                const int il = 32 * wr + 16 * fr + 4 * g + reg;   // D row (m89)
                const int jl = 32 * wc + 16 * fc + c16;           // D col (m89)
                const int i = i0 + il, j = j0 + jl;
                if (i <= j && j < NN)
                    Gb[tri_base(i) + (j - i)] =
                        (float)(fabs((double)acc[fr][fc][reg]) * s_inv[0][il] * s_inv[1][jl]);
            }
}

// ---- device helper: greedy selection for one batch, one wave ----
__device__ __forceinline__ void select_wave(const float* __restrict__ Gb,
                                            int lane, int* s_sorted) {
    float best[5];
    int myidx = 0;

    #pragma unroll
    for (int q = 0; q < 5; ++q) {
        int r = lane + 64 * q;
        best[q] = (r < NN) ? Gb[r] : 3.4e38f;
    }

    int last;
    {
        float v = INFINITY; int ri = 1 << 30;
        #pragma unroll
        for (int q = 0; q < 5; ++q)
            if (best[q] < v) { v = best[q]; ri = lane + 64 * q; }
        #pragma unroll
        for (int off = 32; off >= 1; off >>= 1) {
            float ov = __shfl_xor(v, off, 64); int oi = __shfl_xor(ri, off, 64);
            if (ov < v || (ov == v && oi < ri)) { v = ov; ri = oi; }
        }
        last = ri;
    }
    if (lane == 1) myidx = last;

    for (int t = 2; t < KK; ++t) {
        #pragma unroll
        for (int q = 0; q < 5; ++q) {
            int r = lane + 64 * q;
            if (r < NN) {
                int i = min(last, r), j = max(last, r);
                best[q] = fmaxf(best[q], Gb[tri_base(i) + (j - i)]);
            }
        }
        float v = INFINITY; int ri = 1 << 30;
        #pragma unroll
        for (int q = 0; q < 5; ++q)
            if (best[q] < v) { v = best[q]; ri = lane + 64 * q; }
        #pragma unroll
        for (int off = 32; off >= 1; off >>= 1) {
            float ov = __shfl_xor(v, off, 64); int oi = __shfl_xor(ri, off, 64);
            if (ov < v || (ov == v && oi < ri)) { v = ov; ri = oi; }
        }
        last = ri;
        if (lane == t) myidx = last;
    }

    int rank = 0;
    for (int j = 0; j < KK; ++j) {
        int oj = __shfl(myidx, j, 64);
        rank += (oj < myidx) || (oj == myidx && j < lane);
    }
    s_sorted[rank] = myidx;
}

// ---------------- 2a. fused selection + gather (G in d_ws: race-free) ------
__global__ __launch_bounds__(256) void kfused(const float* __restrict__ G,
                                              const float* __restrict__ video,
                                              const float* __restrict__ audio,
                                              float* __restrict__ out_v,
                                              float* __restrict__ out_a) {
    const int b = blockIdx.x, tid = threadIdx.x;
    __shared__ int s_sorted[KK];

    if (tid < 64)
        select_wave(G + (size_t)b * TRI, tid, s_sorted);
    __syncthreads();

    const float4* vb4 = (const float4*)(video + (size_t)b * NN * DV);
    float4* ov4 = (float4*)(out_v + (size_t)b * KK * DV);
    #pragma unroll 4
    for (int t = tid; t < KK * DV / 4; t += 256) {
        int k = t >> 8, c = t & 255;
        ov4[t] = vb4[s_sorted[k] * (DV / 4) + c];
    }
    const float4* ab4 = (const float4*)(audio + (size_t)b * NN * DA);
    float4* oa4 = (float4*)(out_a + (size_t)b * KK * DA);
    for (int t = tid; t < KK * DA / 4; t += 256) {
        int k = t >> 5, c = t & 31;
        oa4[t] = ab4[s_sorted[k] * (DA / 4) + c];
    }
}

// ---------------- 2b/2c. fallback split path (G in out_v region) ----------
__global__ __launch_bounds__(64) void kselect(const float* __restrict__ G,
                                              float* __restrict__ out_a) {
    __shared__ int s_sorted[KK];
    select_wave(G + (size_t)blockIdx.x * TRI, threadIdx.x, s_sorted);
    __syncthreads();
    ((int*)(out_a + (size_t)blockIdx.x * KK * DA))[threadIdx.x] = s_sorted[threadIdx.x];
}

__global__ __launch_bounds__(256) void kgather(const float* __restrict__ video,
                                               const float* __restrict__ audio,
                                               float* __restrict__ out_v,
                                               float* __restrict__ out_a) {
    int b = blockIdx.x, tid = threadIdx.x;
    __shared__ int s_idx[KK];
    const int* idxp = (const int*)(out_a + (size_t)b * KK * DA);
    if (tid < KK) s_idx[tid] = idxp[tid];
    __syncthreads();

    const float4* vb4 = (const float4*)(video + (size_t)b * NN * DV);
    float4* ov4 = (float4*)(out_v + (size_t)b * KK * DV);
    #pragma unroll 4
    for (int t = tid; t < KK * DV / 4; t += 256) {
        int k = t >> 8, c = t & 255;
        ov4[t] = vb4[s_idx[k] * (DV / 4) + c];
    }
    const float4* ab4 = (const float4*)(audio + (size_t)b * NN * DA);
    float4* oa4 = (float4*)(out_a + (size_t)b * KK * DA);
    for (int t = tid; t < KK * DA / 4; t += 256) {
        int k = t >> 5, c = t & 31;
        oa4[t] = ab4[s_idx[k] * (DA / 4) + c];
    }
}

extern "C" void kernel_launch(void* const* d_in, const int* in_sizes, int n_in,
                              void* d_out, int out_size, void* d_ws, size_t ws_size,
                              hipStream_t stream) {
    const float* video = (const float*)d_in[0];
    const float* audio = (const float*)d_in[1];
    float* out   = (float*)d_out;
    float* out_v = out;
    float* out_a = out + (size_t)BB * KK * DV;

    const size_t g_bytes = (size_t)BB * TRI * sizeof(float);   // 23.1 MB
    if (ws_size >= g_bytes) {
        float* G = (float*)d_ws;
        kgram <<<NTILES * BB, 256, 0, stream>>>(video, G);
        kfused<<<BB, 256, 0, stream>>>(G, video, audio, out_v, out_a);
    } else {
        // G in out_v region: selection reads must complete before gather
        // writes out_v (separate kernels serialize on the stream).
        float* G = out;
        kgram  <<<NTILES * BB, 256, 0, stream>>>(video, G);
        kselect<<<BB, 64, 0, stream>>>(G, out_a);
        kgather<<<BB, 256, 0, stream>>>(video, audio, out_v, out_a);
    }
}

// Round 9
// 206.830 us; speedup vs baseline: 6.3427x; 1.5226x over previous
//
#include <hip/hip_runtime.h>
#include <math.h>

// Greedy farthest-point selection via precomputed Gram triangle.
// kgram: MFMA f16 2-way-split (RNE hi + lo residual, 3 cross-products, f32
//        accum), DOUBLE-BUFFERED LDS (one barrier/chunk: stage chunk k+1 into
//        buf nxt while computing chunk k from buf cur), dual-b64 conflict-free
//        fragment reads (R5-proven geometry), reg prefetch 2 chunks ahead.
// kfused: greedy argmin on G (wave 0) + gather (all waves), one block/batch.
// G scratch in d_ws (23.1 MB): kfused's G reads never overlap its out writes.
// Fallback if ws_size too small: R5-proven 3-kernel path (G in out_v region).

constexpr int BB = 128, NN = 300, DV = 1024, DA = 128, KK = 64;
constexpr int TRI = NN * (NN + 1) / 2;        // 45150
constexpr int TB = 64;
constexpr int NTILES = 15;                    // upper-tri 64x64 tiles of 300x300
constexpr int KC = 32;                        // K chunk (one K=32 MFMA step)
constexpr int NCH = DV / KC;                  // 32 chunks
constexpr int LDH = 36;                       // f16 row stride: 72 B, 8B-aligned

__device__ __constant__ int c_ib[NTILES] = {0,0,0,0,0, 1,1,1,1, 2,2,2, 3,3, 4};
__device__ __constant__ int c_jb[NTILES] = {0,1,2,3,4, 1,2,3,4, 2,3,4, 3,4, 4};

typedef _Float16 f16x8 __attribute__((ext_vector_type(8)));
typedef float    f32x4 __attribute__((ext_vector_type(4)));

union H4 { _Float16 h[4]; uint2 u; };
union F8 { uint2 u2[2]; f16x8 v; };

__device__ __forceinline__ int tri_base(int i) { return i * NN - (i * (i - 1)) / 2; }

// ---------------- 1. Gram triangle via f16-split MFMA ----------------
// Grid 1920 = 15 tiles x 128 batches, XCD-swizzled (each XCD owns 16 batches).
// 4 waves; wave w -> 32x32 quadrant (wr=w>>1, wc=w&1) as 2x2 16x16x32 frags.
// k-map: fragment slot (g,e) reads chunk-k position {4g+e | e<4} u {16+4g+e-4};
// staging writes source-k linearly -> same permutation for A and B -> dot
// invariant (R5-validated end-to-end through all 8064 argmin decisions).
__global__ __launch_bounds__(256) void kgram(const float* __restrict__ video,
                                             float* __restrict__ G) {
    const int bid  = blockIdx.x;
    const int swz  = (bid & 7) * 240 + (bid >> 3);      // bijective: 1920=8*240
    const int batch = swz / 15;
    const int tile  = swz - batch * 15;
    const int i0 = c_ib[tile] * TB, j0 = c_jb[tile] * TB;
    const bool diag = (i0 == j0);
    const int tid = threadIdx.x;

    __shared__ _Float16 sH[2][4][TB][LDH];   // [buf][A-hi,A-lo,B-hi,B-lo] 36.9 KB
    __shared__ float    s_part[256];
    __shared__ double   s_inv[2][TB];

    const float* vb = video + (size_t)batch * NN * DV;

    // staging role: thread -> (slab, row, k-half); 16 floats per chunk
    const int slab  = tid >> 7;           // 0=A(i-rows), 1=B(j-rows)
    const int lrow  = (tid >> 1) & 63;
    const int khalf = tid & 1;
    const int grow  = (slab ? j0 : i0) + lrow;
    const bool rok  = grow < NN;
    const bool stage_on = !(diag && slab == 1);   // diag: B slab = A slab
    const float4* srcb4 = (const float4*)(vb + (size_t)(rok ? grow : 0) * DV);
    const int qbase = khalf * 4;          // float4 index within chunk

    // compute role
    const int lane = tid & 63, w = tid >> 6;
    const int wr = w >> 1, wc = w & 1;
    const int g = lane >> 4, c16 = lane & 15;
    const int bplane = diag ? 0 : 2;

    f32x4 acc[2][2];
    #pragma unroll
    for (int fr = 0; fr < 2; ++fr)
        #pragma unroll
        for (int fc = 0; fc < 2; ++fc) acc[fr][fc] = (f32x4){0.f, 0.f, 0.f, 0.f};

    float ps = 0.f;
    float4 ld[4];
    const float4 z4 = make_float4(0.f, 0.f, 0.f, 0.f);

    // stage chunk `ck` into buffer `bf` from ld regs, accumulate norm partial
    auto stage_write = [&](int bf) {
        #pragma unroll
        for (int q = 0; q < 4; ++q) {
            float4 v = ld[q];
            ps = fmaf(v.x, v.x, fmaf(v.y, v.y, fmaf(v.z, v.z, fmaf(v.w, v.w, ps))));
            H4 hi, lo;
            _Float16 h0 = (_Float16)v.x, h1 = (_Float16)v.y,
                     h2 = (_Float16)v.z, h3 = (_Float16)v.w;
            hi.h[0] = h0; hi.h[1] = h1; hi.h[2] = h2; hi.h[3] = h3;
            lo.h[0] = (_Float16)(v.x - (float)h0);
            lo.h[1] = (_Float16)(v.y - (float)h1);
            lo.h[2] = (_Float16)(v.z - (float)h2);
            lo.h[3] = (_Float16)(v.w - (float)h3);
            const int p = khalf * 16 + 4 * q;            // linear source k
            *(uint2*)&sH[bf][slab * 2 + 0][lrow][p] = hi.u;
            *(uint2*)&sH[bf][slab * 2 + 1][lrow][p] = lo.u;
        }
    };

    // ---- prologue: chunk 0 staged into buf 0; chunk 1 in regs ----
    if (stage_on) {
        #pragma unroll
        for (int q = 0; q < 4; ++q) ld[q] = rok ? srcb4[qbase + q] : z4;
        stage_write(0);
        #pragma unroll
        for (int q = 0; q < 4; ++q) ld[q] = rok ? srcb4[8 + qbase + q] : z4;
    }
    __syncthreads();

    for (int kc = 0; kc < NCH; ++kc) {
        const int cur = kc & 1, nxt = cur ^ 1;

        // stage chunk kc+1 into buf nxt (read by no one until next iter)
        if (stage_on && kc < NCH - 1) stage_write(nxt);
        // prefetch chunk kc+2 into regs
        if (stage_on && kc < NCH - 2) {
            #pragma unroll
            for (int q = 0; q < 4; ++q)
                ld[q] = rok ? srcb4[(kc + 2) * 8 + qbase + q] : z4;
        }

        // compute chunk kc from buf cur (dual-b64 reads: conflict-free, R5)
        f16x8 Ah[2], Al[2], Bh[2], Bl[2];
        #pragma unroll
        for (int fr = 0; fr < 2; ++fr) {
            const int row = 32 * wr + 16 * fr + c16;
            F8 t;
            t.u2[0] = *(const uint2*)&sH[cur][0][row][4 * g];
            t.u2[1] = *(const uint2*)&sH[cur][0][row][16 + 4 * g];
            Ah[fr] = t.v;
            t.u2[0] = *(const uint2*)&sH[cur][1][row][4 * g];
            t.u2[1] = *(const uint2*)&sH[cur][1][row][16 + 4 * g];
            Al[fr] = t.v;
        }
        #pragma unroll
        for (int fc = 0; fc < 2; ++fc) {
            const int row = 32 * wc + 16 * fc + c16;
            F8 t;
            t.u2[0] = *(const uint2*)&sH[cur][bplane + 0][row][4 * g];
            t.u2[1] = *(const uint2*)&sH[cur][bplane + 0][row][16 + 4 * g];
            Bh[fc] = t.v;
            t.u2[0] = *(const uint2*)&sH[cur][bplane + 1][row][4 * g];
            t.u2[1] = *(const uint2*)&sH[cur][bplane + 1][row][16 + 4 * g];
            Bl[fc] = t.v;
        }
        #pragma unroll
        for (int fr = 0; fr < 2; ++fr)
            #pragma unroll
            for (int fc = 0; fc < 2; ++fc) {
                acc[fr][fc] = __builtin_amdgcn_mfma_f32_16x16x32_f16(Ah[fr], Bh[fc], acc[fr][fc], 0, 0, 0);
                acc[fr][fc] = __builtin_amdgcn_mfma_f32_16x16x32_f16(Ah[fr], Bl[fc], acc[fr][fc], 0, 0, 0);
                acc[fr][fc] = __builtin_amdgcn_mfma_f32_16x16x32_f16(Al[fr], Bh[fc], acc[fr][fc], 0, 0, 0);
            }

        __syncthreads();   // one barrier per chunk: nxt fully staged, cur consumed
    }

    // ---- norms ----
    s_part[tid] = ps;
    __syncthreads();
    if (tid < 128) {
        const int st = tid >> 6, r = tid & 63;
        const int src = (st && !diag) ? 128 + 2 * r : 2 * r;   // diag: reuse A partials
        float ssum = s_part[src] + s_part[src + 1];
        s_inv[st][r] = 1.0 / (sqrt((double)ssum) + 1e-5);
    }
    __syncthreads();

    float* Gb = G + (size_t)batch * TRI;
    #pragma unroll
    for (int fr = 0; fr < 2; ++fr)
        #pragma unroll
        for (int fc = 0; fc < 2; ++fc)
            #pragma unroll
            for (int reg = 0; reg < 4; ++reg) {
                const int il = 32 * wr + 16 * fr + 4 * g + reg;   // D row (m89)
                const int jl = 32 * wc + 16 * fc + c16;           // D col (m89)
                const int i = i0 + il, j = j0 + jl;
                if (i <= j && j < NN)
                    Gb[tri_base(i) + (j - i)] =
                        (float)(fabs((double)acc[fr][fc][reg]) * s_inv[0][il] * s_inv[1][jl]);
            }
}

// ---- device helper: greedy selection for one batch, one wave ----
__device__ __forceinline__ void select_wave(const float* __restrict__ Gb,
                                            int lane, int* s_sorted) {
    float best[5];
    int myidx = 0;

    #pragma unroll
    for (int q = 0; q < 5; ++q) {
        int r = lane + 64 * q;
        best[q] = (r < NN) ? Gb[r] : 3.4e38f;
    }

    int last;
    {
        float v = INFINITY; int ri = 1 << 30;
        #pragma unroll
        for (int q = 0; q < 5; ++q)
            if (best[q] < v) { v = best[q]; ri = lane + 64 * q; }
        #pragma unroll
        for (int off = 32; off >= 1; off >>= 1) {
            float ov = __shfl_xor(v, off, 64); int oi = __shfl_xor(ri, off, 64);
            if (ov < v || (ov == v && oi < ri)) { v = ov; ri = oi; }
        }
        last = ri;
    }
    if (lane == 1) myidx = last;

    for (int t = 2; t < KK; ++t) {
        #pragma unroll
        for (int q = 0; q < 5; ++q) {
            int r = lane + 64 * q;
            if (r < NN) {
                int i = min(last, r), j = max(last, r);
                best[q] = fmaxf(best[q], Gb[tri_base(i) + (j - i)]);
            }
        }
        float v = INFINITY; int ri = 1 << 30;
        #pragma unroll
        for (int q = 0; q < 5; ++q)
            if (best[q] < v) { v = best[q]; ri = lane + 64 * q; }
        #pragma unroll
        for (int off = 32; off >= 1; off >>= 1) {
            float ov = __shfl_xor(v, off, 64); int oi = __shfl_xor(ri, off, 64);
            if (ov < v || (ov == v && oi < ri)) { v = ov; ri = oi; }
        }
        last = ri;
        if (lane == t) myidx = last;
    }

    int rank = 0;
    for (int j = 0; j < KK; ++j) {
        int oj = __shfl(myidx, j, 64);
        rank += (oj < myidx) || (oj == myidx && j < lane);
    }
    s_sorted[rank] = myidx;
}

// ---------------- 2a. fused selection + gather (G in d_ws: race-free) ------
__global__ __launch_bounds__(256) void kfused(const float* __restrict__ G,
                                              const float* __restrict__ video,
                                              const float* __restrict__ audio,
                                              float* __restrict__ out_v,
                                              float* __restrict__ out_a) {
    const int b = blockIdx.x, tid = threadIdx.x;
    __shared__ int s_sorted[KK];

    if (tid < 64)
        select_wave(G + (size_t)b * TRI, tid, s_sorted);
    __syncthreads();

    const float4* vb4 = (const float4*)(video + (size_t)b * NN * DV);
    float4* ov4 = (float4*)(out_v + (size_t)b * KK * DV);
    #pragma unroll 4
    for (int t = tid; t < KK * DV / 4; t += 256) {
        int k = t >> 8, c = t & 255;
        ov4[t] = vb4[s_sorted[k] * (DV / 4) + c];
    }
    const float4* ab4 = (const float4*)(audio + (size_t)b * NN * DA);
    float4* oa4 = (float4*)(out_a + (size_t)b * KK * DA);
    for (int t = tid; t < KK * DA / 4; t += 256) {
        int k = t >> 5, c = t & 31;
        oa4[t] = ab4[s_sorted[k] * (DA / 4) + c];
    }
}

// ---------------- 2b/2c. fallback split path (G in out_v region) ----------
__global__ __launch_bounds__(64) void kselect(const float* __restrict__ G,
                                              float* __restrict__ out_a) {
    __shared__ int s_sorted[KK];
    select_wave(G + (size_t)blockIdx.x * TRI, threadIdx.x, s_sorted);
    __syncthreads();
    ((int*)(out_a + (size_t)blockIdx.x * KK * DA))[threadIdx.x] = s_sorted[threadIdx.x];
}

__global__ __launch_bounds__(256) void kgather(const float* __restrict__ video,
                                               const float* __restrict__ audio,
                                               float* __restrict__ out_v,
                                               float* __restrict__ out_a) {
    int b = blockIdx.x, tid = threadIdx.x;
    __shared__ int s_idx[KK];
    const int* idxp = (const int*)(out_a + (size_t)b * KK * DA);
    if (tid < KK) s_idx[tid] = idxp[tid];
    __syncthreads();

    const float4* vb4 = (const float4*)(video + (size_t)b * NN * DV);
    float4* ov4 = (float4*)(out_v + (size_t)b * KK * DV);
    #pragma unroll 4
    for (int t = tid; t < KK * DV / 4; t += 256) {
        int k = t >> 8, c = t & 255;
        ov4[t] = vb4[s_idx[k] * (DV / 4) + c];
    }
    const float4* ab4 = (const float4*)(audio + (size_t)b * NN * DA);
    float4* oa4 = (float4*)(out_a + (size_t)b * KK * DA);
    for (int t = tid; t < KK * DA / 4; t += 256) {
        int k = t >> 5, c = t & 31;
        oa4[t] = ab4[s_idx[k] * (DA / 4) + c];
    }
}

extern "C" void kernel_launch(void* const* d_in, const int* in_sizes, int n_in,
                              void* d_out, int out_size, void* d_ws, size_t ws_size,
                              hipStream_t stream) {
    const float* video = (const float*)d_in[0];
    const float* audio = (const float*)d_in[1];
    float* out   = (float*)d_out;
    float* out_v = out;
    float* out_a = out + (size_t)BB * KK * DV;

    const size_t g_bytes = (size_t)BB * TRI * sizeof(float);   // 23.1 MB
    if (ws_size >= g_bytes) {
        float* G = (float*)d_ws;
        kgram <<<NTILES * BB, 256, 0, stream>>>(video, G);
        kfused<<<BB, 256, 0, stream>>>(G, video, audio, out_v, out_a);
    } else {
        float* G = out;
        kgram  <<<NTILES * BB, 256, 0, stream>>>(video, G);
        kselect<<<BB, 64, 0, stream>>>(G, out_a);
        kgather<<<BB, 256, 0, stream>>>(video, audio, out_v, out_a);
    }
}